// Round 4
// baseline (2773.815 us; speedup 1.0000x reference)
//
#include <hip/hip_runtime.h>

#define C 128
#define NN 50000      // N_USER == N_ITEM
#define NP 50048      // padded rows: 391 * 128
#define NE 600000
#define LN_EPS 1e-5f
#define NBKT 782      // buckets per edge type: ceil(50000/64)
#define BPAD 1024
#define CHUNK 8192
#define CAP 1280      // bucket capacity (avg load 768, +9 sigma safety)

typedef __attribute__((ext_vector_type(8))) short short8;
typedef __attribute__((ext_vector_type(4))) float f32x4;
typedef unsigned short u16;
typedef unsigned int u32;

union V16 { uint4 u; short8 s; };

__device__ inline float lo16f(u32 v) { union { u32 i; float f; } x; x.i = v << 16; return x.f; }
__device__ inline float hi16f(u32 v) { union { u32 i; float f; } x; x.i = v & 0xffff0000u; return x.f; }
__device__ inline u16 f2bf(float f) {
  union { float f; u32 i; } x; x.f = f;
  u32 r = (x.i + 0x7fffu + ((x.i >> 16) & 1u)) >> 16;   // RNE
  return (u16)r;
}

// ---------------- single-pass LDS-binned bucket scatter ----------------
// Groups edges by dst bucket (dst>>6). Payload u32 = (b<<22)|(dst&63)<<16|src.
// Per-WG: LDS hist -> scan -> one global cursor atomic per bucket -> contiguous run writes.
__global__ __launch_bounds__(256) void bin_kernel(
    u32* __restrict__ bdata, int* __restrict__ cursor,
    const int* e0, const int* e1, const int* e2) {
  __shared__ int hist[BPAD];
  __shared__ int startk[BPAD];
  __shared__ int fillc[BPAD];
  __shared__ int gbase[BPAD];
  __shared__ u32 stage[CHUNK];
  __shared__ int wsum[4];
  const int nchunk = (NE + CHUNK - 1) / CHUNK;    // 74
  int tid = threadIdx.x, lane = tid & 63, wv = tid >> 6;
  int t = blockIdx.x / nchunk, ck = blockIdx.x % nchunk;
  const int* ei  = (t == 0) ? e0 : (t == 1) ? e1 : e2;
  const int* src = ei;
  const int* dst = ei + NE;
  int base = ck * CHUNK;
  int cnt = min(CHUNK, NE - base);

  for (int i = tid; i < BPAD; i += 256) hist[i] = 0;
  __syncthreads();
  for (int k = tid; k < cnt; k += 256)
    atomicAdd(&hist[dst[base + k] >> 6], 1);
  __syncthreads();

  // exclusive scan over BPAD (thread owns 4)
  int h0 = hist[tid * 4], h1 = hist[tid * 4 + 1], h2 = hist[tid * 4 + 2], h3 = hist[tid * 4 + 3];
  int s = h0 + h1 + h2 + h3;
  int incl = s;
  #pragma unroll
  for (int d = 1; d < 64; d <<= 1) { int x = __shfl_up(incl, d, 64); if (lane >= d) incl += x; }
  if (lane == 63) wsum[wv] = incl;
  __syncthreads();
  int wbase = 0;
  for (int w = 0; w < wv; w++) wbase += wsum[w];
  int excl = wbase + incl - s;
  startk[tid * 4]     = excl;
  startk[tid * 4 + 1] = excl + h0;
  startk[tid * 4 + 2] = excl + h0 + h1;
  startk[tid * 4 + 3] = excl + h0 + h1 + h2;
  #pragma unroll
  for (int j = 0; j < 4; j++) {
    int b = tid * 4 + j;
    int c = hist[b];
    fillc[b] = startk[b];
    gbase[b] = (c > 0 && b < NBKT) ? atomicAdd(&cursor[t * NBKT + b], c) : 0;
  }
  __syncthreads();
  for (int k = tid; k < cnt; k += 256) {
    int d = dst[base + k], sv = src[base + k];
    int b = d >> 6;
    int slot = atomicAdd(&fillc[b], 1);
    stage[slot] = ((u32)b << 22) | ((u32)(d & 63) << 16) | (u32)sv;
  }
  __syncthreads();
  for (int i = tid; i < cnt; i += 256) {
    u32 u = stage[i];
    int b = u >> 22;
    int pos = gbase[b] + (i - startk[b]);
    if (pos < CAP)
      bdata[(size_t)(t * NBKT + b) * CAP + pos] = u & 0x3fffff;
  }
}

// ---------------- prep: fp32->bf16 features + weight concat/pack (one dispatch) -------
// Wu[c][k]: k<128 Wl_iu; 128..255 Wr_iu+Wr_uu; 256..383 Wl_uu   (Ktot=384)
// Wi[c][k]: k<128 Wl_ui; 128..255 Wr_ui                          (Ktot=256)
struct PrepArgs {
  const float *xu, *xi;
  const float *Wl_iu[2], *Wr_iu[2], *Wr_uu[2], *Wl_uu[2], *Wl_ui[2], *Wr_ui[2];
  const float *b_iu[2], *b_uu[2], *b_ui[2];
  u16 *xb_u, *xb_i;
  u16 *Wu[2], *Wi[2];
  float *bu[2], *bi[2];
};
#define PK (128 * 384 + 128 * 256 + 256)
__global__ void prep_kernel(PrepArgs a) {
  const int n4 = NN * C / 4;
  int id = blockIdx.x * 256 + threadIdx.x;
  if (id < 2 * n4) {
    int second = id >= n4;
    int j = second ? id - n4 : id;
    float4 v = ((const float4*)(second ? a.xi : a.xu))[j];
    ushort4 o = make_ushort4(f2bf(v.x), f2bf(v.y), f2bf(v.z), f2bf(v.w));
    ((ushort4*)(second ? a.xb_i : a.xb_u))[j] = o;
    return;
  }
  int id2 = id - 2 * n4;
  if (id2 >= 2 * PK) return;
  int l = id2 / PK, j = id2 % PK;
  const int NU = 128 * 384, NI = 128 * 256;
  if (j < NU) {
    int c = j / 384, k = j % 384;
    float v = (k < 128) ? a.Wl_iu[l][c * 128 + k]
            : (k < 256) ? (a.Wr_iu[l][c * 128 + k - 128] + a.Wr_uu[l][c * 128 + k - 128])
                        : a.Wl_uu[l][c * 128 + k - 256];
    a.Wu[l][j] = f2bf(v);
  } else if (j < NU + NI) {
    int q = j - NU;
    int c = q / 256, k = q % 256;
    float v = (k < 128) ? a.Wl_ui[l][c * 128 + k] : a.Wr_ui[l][c * 128 + k - 128];
    a.Wi[l][q] = f2bf(v);
  } else {
    int q = j - NU - NI;
    if (q < 128) a.bu[l][q] = a.b_iu[l][q] + a.b_uu[l][q];
    else a.bi[l][q - 128] = a.b_ui[l][q - 128];
  }
}

// ---------------- bucket aggregation: one WG per bucket, LDS fp32 accumulators -------
// quarter-wave per edge: 16 edges in flight per block; lane gathers 8 channels (uint4).
// accum padded to 132 floats/row so concurrent ds_add spreads banks (~4-way, ~free).
__global__ __launch_bounds__(256) void aggregate_buckets(
    u16* __restrict__ mA, u16* __restrict__ mB, u16* __restrict__ mC,
    const u16* __restrict__ xu, const u16* __restrict__ xi,
    const u32* __restrict__ bdata, const int* __restrict__ cursor) {
  __shared__ float accum[64 * 132];
  __shared__ int deg[64];
  int tid = threadIdx.x;
  int id = blockIdx.x;                   // 0..3*NBKT-1
  int t = id / NBKT, b = id % NBKT;
  const u16* xs = (t == 1) ? xi : xu;
  u16* mean = (t == 0) ? mA : (t == 1) ? mB : mC;
  int cnt = min(cursor[id], CAP);
  for (int i = tid; i < 64 * 132; i += 256) accum[i] = 0.f;
  if (tid < 64) deg[tid] = 0;
  __syncthreads();
  int lane = tid & 63, wv = tid >> 6, q = lane >> 4, ql = lane & 15;
  const u32* bd = bdata + (size_t)id * CAP;
  for (int e = wv * 4 + q; e < cnt; e += 16) {
    u32 u = bd[e];
    int sv = u & 0xffff, dl = (u >> 16) & 63;
    uint4 v = *(const uint4*)(xs + (size_t)sv * C + ql * 8);
    float* ap = &accum[dl * 132 + ql * 8];
    atomicAdd(ap + 0, lo16f(v.x)); atomicAdd(ap + 1, hi16f(v.x));
    atomicAdd(ap + 2, lo16f(v.y)); atomicAdd(ap + 3, hi16f(v.y));
    atomicAdd(ap + 4, lo16f(v.z)); atomicAdd(ap + 5, hi16f(v.z));
    atomicAdd(ap + 6, lo16f(v.w)); atomicAdd(ap + 7, hi16f(v.w));
    if (ql == 0) atomicAdd(&deg[dl], 1);
  }
  __syncthreads();
  // write means: 64 nodes x 64 u32 (bf16x2) = 4096 words
  for (int i = tid; i < 64 * 64; i += 256) {
    int dl = i >> 6, cp = i & 63;
    int n = b * 64 + dl;
    if (n < NN) {
      float inv = 1.0f / fmaxf((float)deg[dl], 1.0f);
      float va = accum[dl * 132 + cp * 2] * inv;
      float vb = accum[dl * 132 + cp * 2 + 1] * inv;
      ((u32*)(mean + (size_t)n * C))[cp] = (u32)f2bf(va) | ((u32)f2bf(vb) << 16);
    }
  }
}

// ---------------- fused MFMA GEMM (+bias) + LayerNorm + ReLU, both node types -------
// gridDim = (391, 2): y==0 item side (nseg=2, Ktot=256), y==1 user side (nseg=3, Ktot=384).
// BM=128 (4 waves x 32 rows), BN=128. W K-segment staged in LDS (136-u16 rows).
struct GemmArgs {
  const u16 *Ai0, *Ai1;
  const u16 *Wi; const float *bi, *lnwi, *lnbi; float* outfi; u16* outbi;
  const u16 *Au0, *Au1, *Au2;
  const u16 *Wu; const float *bu, *lnwu, *lnbu; float* outfu; u16* outbu;
};
__global__ __launch_bounds__(256) void gemm2_ln_relu(GemmArgs g) {
  __shared__ u16 Wt[128][136];
  int tid = threadIdx.x, lane = tid & 63, wv = tid >> 6;
  int arow = lane & 15, kq = (lane >> 4) * 8;
  int n0 = blockIdx.x * 128 + wv * 32;
  int user = blockIdx.y;
  const u16* As[3];
  const u16* W; const float *bias, *lnw, *lnb; float* outf; u16* outb;
  int nseg, Ktot;
  if (user) {
    As[0] = g.Au0; As[1] = g.Au1; As[2] = g.Au2; nseg = 3; Ktot = 384;
    W = g.Wu; bias = g.bu; lnw = g.lnwu; lnb = g.lnbu; outf = g.outfu; outb = g.outbu;
  } else {
    As[0] = g.Ai0; As[1] = g.Ai1; As[2] = nullptr; nseg = 2; Ktot = 256;
    W = g.Wi; bias = g.bi; lnw = g.lnwi; lnb = g.lnbi; outf = g.outfi; outb = g.outbi;
  }
  f32x4 acc[2][8];
  #pragma unroll
  for (int gg = 0; gg < 2; gg++)
    #pragma unroll
    for (int t = 0; t < 8; t++) acc[gg][t] = (f32x4){0.f, 0.f, 0.f, 0.f};

  for (int sg = 0; sg < nseg; sg++) {
    __syncthreads();
    #pragma unroll
    for (int it = 0; it < 8; it++) {            // stage 128x128 W segment (32 KB)
      int chunk = it * 256 + tid;
      int c = chunk >> 4, k8 = (chunk & 15) * 8;
      uint4 v = *(const uint4*)(W + (size_t)c * Ktot + sg * 128 + k8);
      *(uint4*)&Wt[c][k8] = v;
    }
    __syncthreads();
    const u16* Ar0 = As[sg] + (size_t)(n0 + arow) * C + kq;
    const u16* Ar1 = As[sg] + (size_t)(n0 + 16 + arow) * C + kq;
    V16 a0[4], a1[4];
    #pragma unroll
    for (int c4 = 0; c4 < 4; c4++) {
      a0[c4].u = *(const uint4*)(Ar0 + c4 * 32);
      a1[c4].u = *(const uint4*)(Ar1 + c4 * 32);
    }
    #pragma unroll
    for (int c4 = 0; c4 < 4; c4++) {
      #pragma unroll
      for (int t = 0; t < 8; t++) {
        short8 bfr = *(const short8*)&Wt[t * 16 + arow][kq + c4 * 32];
        acc[0][t] = __builtin_amdgcn_mfma_f32_16x16x32_bf16(a0[c4].s, bfr, acc[0][t], 0, 0, 0);
        acc[1][t] = __builtin_amdgcn_mfma_f32_16x16x32_bf16(a1[c4].s, bfr, acc[1][t], 0, 0, 0);
      }
    }
  }
  float bv[8], lnwv[8], lnbv[8];
  #pragma unroll
  for (int t = 0; t < 8; t++) {
    int c = t * 16 + arow;
    bv[t] = bias[c]; lnwv[t] = lnw[c]; lnbv[t] = lnb[c];
  }
  #pragma unroll
  for (int gg = 0; gg < 2; gg++) {
    #pragma unroll
    for (int r = 0; r < 4; r++) {
      float s1 = 0.f, s2 = 0.f;
      #pragma unroll
      for (int t = 0; t < 8; t++) {
        float v = acc[gg][t][r] + bv[t];
        s1 += v; s2 += v * v;
      }
      #pragma unroll
      for (int d = 1; d < 16; d <<= 1) {
        s1 += __shfl_xor(s1, d, 64);
        s2 += __shfl_xor(s2, d, 64);
      }
      float mu = s1 * (1.f / 128.f);
      float var = s2 * (1.f / 128.f) - mu * mu;
      float rs = rsqrtf(var + LN_EPS);
      int gr = n0 + gg * 16 + (lane >> 4) * 4 + r;
      if (gr < NN) {
        #pragma unroll
        for (int t = 0; t < 8; t++) {
          float y = (acc[gg][t][r] + bv[t] - mu) * rs * lnwv[t] + lnbv[t];
          y = fmaxf(y, 0.f);
          int c = t * 16 + arow;
          if (outf) outf[(size_t)gr * C + c] = y;
          else      outb[(size_t)gr * C + c] = f2bf(y);
        }
      }
    }
  }
}

extern "C" void kernel_launch(void* const* d_in, const int* in_sizes, int n_in,
                              void* d_out, int out_size, void* d_ws, size_t ws_size,
                              hipStream_t stream) {
  const float* xu = (const float*)d_in[0];
  const float* xi = (const float*)d_in[1];
  const int* ei[3] = { (const int*)d_in[2], (const int*)d_in[3], (const int*)d_in[4] };
  const float* P[26];
  for (int k = 0; k < 26; k++) P[k] = (const float*)d_in[5 + k];
  // per layer l, Q = P+13l: [0]Wl_ui [1]b_ui [2]Wr_ui [3]Wl_iu [4]b_iu [5]Wr_iu
  //                         [6]Wl_uu [7]b_uu [8]Wr_uu [9]lnw_u [10]lnb_u [11]lnw_i [12]lnb_i

  // ---- workspace (~77 MB) ----
  char* p = (char*)d_ws;
  auto alloc = [&](size_t bytes) { char* r = p; p += (bytes + 255) & ~(size_t)255; return r; };
  u32* bdata  = (u32*)alloc((size_t)3 * NBKT * CAP * 4);
  int* cursor = (int*)alloc((size_t)3 * NBKT * 4);
  u16* xb_u  = (u16*)alloc((size_t)NP * C * 2);
  u16* xb_i  = (u16*)alloc((size_t)NP * C * 2);
  u16* meanA = (u16*)alloc((size_t)NP * C * 2);
  u16* meanB = (u16*)alloc((size_t)NP * C * 2);
  u16* meanC = (u16*)alloc((size_t)NP * C * 2);
  u16 *Wu[2], *Wi[2]; float *bu[2], *bi[2];
  for (int l = 0; l < 2; l++) {
    Wu[l] = (u16*)alloc(128 * 384 * 2);
    Wi[l] = (u16*)alloc(128 * 256 * 2);
    bu[l] = (float*)alloc(128 * 4);
    bi[l] = (float*)alloc(128 * 4);
  }

  // ---- bucket binning (edges layer-invariant) ----
  hipMemsetAsync(cursor, 0, (size_t)3 * NBKT * 4, stream);
  const int nchunk = (NE + CHUNK - 1) / CHUNK;   // 74
  bin_kernel<<<3 * nchunk, 256, 0, stream>>>(bdata, cursor, ei[0], ei[1], ei[2]);

  // ---- prep: bf16 features + packed weights ----
  PrepArgs pa;
  pa.xu = xu; pa.xi = xi; pa.xb_u = xb_u; pa.xb_i = xb_i;
  for (int l = 0; l < 2; l++) {
    const float* const* Q = P + 13 * l;
    pa.Wl_iu[l] = Q[3]; pa.Wr_iu[l] = Q[5]; pa.Wr_uu[l] = Q[8]; pa.Wl_uu[l] = Q[6];
    pa.Wl_ui[l] = Q[0]; pa.Wr_ui[l] = Q[2];
    pa.b_iu[l] = Q[4]; pa.b_uu[l] = Q[7]; pa.b_ui[l] = Q[1];
    pa.Wu[l] = Wu[l]; pa.Wi[l] = Wi[l]; pa.bu[l] = bu[l]; pa.bi[l] = bi[l];
  }
  const int n4 = NN * C / 4;
  const int prep_total = 2 * n4 + 2 * PK;
  prep_kernel<<<(prep_total + 255) / 256, 256, 0, stream>>>(pa);

  for (int l = 0; l < 2; l++) {
    const float* const* Q = P + 13 * l;
    aggregate_buckets<<<3 * NBKT, 256, 0, stream>>>(meanA, meanB, meanC, xb_u, xb_i,
                                                    bdata, cursor);
    GemmArgs g;
    g.Ai0 = meanA; g.Ai1 = xb_i; g.Wi = Wi[l]; g.bi = bi[l]; g.lnwi = Q[11]; g.lnbi = Q[12];
    g.Au0 = meanB; g.Au1 = xb_u; g.Au2 = meanC; g.Wu = Wu[l]; g.bu = bu[l];
    g.lnwu = Q[9]; g.lnbu = Q[10];
    if (l == 0) {
      g.outfi = nullptr; g.outbi = xb_i;   // in place (block reads only its own rows)
      g.outfu = nullptr; g.outbu = xb_u;
    } else {
      g.outfi = (float*)d_out + (size_t)NN * C; g.outbi = nullptr;
      g.outfu = (float*)d_out;                  g.outbu = nullptr;
    }
    gemm2_ln_relu<<<dim3(NP / 128, 2), 256, 0, stream>>>(g);
  }
  (void)in_sizes; (void)n_in; (void)out_size; (void)ws_size;
}

// Round 5
// 403.019 us; speedup vs baseline: 6.8826x; 6.8826x over previous
//
#include <hip/hip_runtime.h>

#define C 128
#define NN 50000      // N_USER == N_ITEM
#define NP 50048      // padded rows: 391 * 128
#define NE 600000
#define LN_EPS 1e-5f
#define NBKT 782      // buckets per edge type: ceil(50000/64)
#define BPAD 1024
#define CHUNK 8192
#define CAP 1280      // bucket capacity (avg load 768, +18 sigma)

typedef __attribute__((ext_vector_type(8))) short short8;
typedef __attribute__((ext_vector_type(4))) float f32x4;
typedef unsigned short u16;
typedef unsigned int u32;

union V16 { uint4 u; short8 s; };

__device__ inline float lo16f(u32 v) { union { u32 i; float f; } x; x.i = v << 16; return x.f; }
__device__ inline float hi16f(u32 v) { union { u32 i; float f; } x; x.i = v & 0xffff0000u; return x.f; }
__device__ inline u16 f2bf(float f) {
  union { float f; u32 i; } x; x.f = f;
  u32 r = (x.i + 0x7fffu + ((x.i >> 16) & 1u)) >> 16;   // RNE
  return (u16)r;
}

// ---------------- single-pass LDS-binned bucket scatter ----------------
// Groups edges by dst bucket (dst>>6). Stored payload u32 = (dst&63)<<16 | src.
__global__ __launch_bounds__(256) void bin_kernel(
    u32* __restrict__ bdata, int* __restrict__ cursor,
    const int* e0, const int* e1, const int* e2) {
  __shared__ int hist[BPAD];
  __shared__ int startk[BPAD];
  __shared__ int fillc[BPAD];
  __shared__ int gbase[BPAD];
  __shared__ u32 stage[CHUNK];
  __shared__ int wsum[4];
  const int nchunk = (NE + CHUNK - 1) / CHUNK;    // 74
  int tid = threadIdx.x, lane = tid & 63, wv = tid >> 6;
  int t = blockIdx.x / nchunk, ck = blockIdx.x % nchunk;
  const int* ei  = (t == 0) ? e0 : (t == 1) ? e1 : e2;
  const int* src = ei;
  const int* dst = ei + NE;
  int base = ck * CHUNK;
  int cnt = min(CHUNK, NE - base);

  for (int i = tid; i < BPAD; i += 256) hist[i] = 0;
  __syncthreads();
  for (int k = tid; k < cnt; k += 256)
    atomicAdd(&hist[dst[base + k] >> 6], 1);
  __syncthreads();

  // exclusive scan over BPAD (thread owns 4)
  int h0 = hist[tid * 4], h1 = hist[tid * 4 + 1], h2 = hist[tid * 4 + 2], h3 = hist[tid * 4 + 3];
  int s = h0 + h1 + h2 + h3;
  int incl = s;
  #pragma unroll
  for (int d = 1; d < 64; d <<= 1) { int x = __shfl_up(incl, d, 64); if (lane >= d) incl += x; }
  if (lane == 63) wsum[wv] = incl;
  __syncthreads();
  int wbase = 0;
  for (int w = 0; w < wv; w++) wbase += wsum[w];
  int excl = wbase + incl - s;
  startk[tid * 4]     = excl;
  startk[tid * 4 + 1] = excl + h0;
  startk[tid * 4 + 2] = excl + h0 + h1;
  startk[tid * 4 + 3] = excl + h0 + h1 + h2;
  #pragma unroll
  for (int j = 0; j < 4; j++) {
    int b = tid * 4 + j;
    int c = hist[b];
    fillc[b] = startk[b];
    gbase[b] = (c > 0 && b < NBKT) ? atomicAdd(&cursor[t * NBKT + b], c) : 0;
  }
  __syncthreads();
  for (int k = tid; k < cnt; k += 256) {
    int d = dst[base + k], sv = src[base + k];
    int b = d >> 6;
    int slot = atomicAdd(&fillc[b], 1);
    stage[slot] = ((u32)b << 22) | ((u32)(d & 63) << 16) | (u32)sv;
  }
  __syncthreads();
  for (int i = tid; i < cnt; i += 256) {
    u32 u = stage[i];
    int b = u >> 22;
    int pos = gbase[b] + (i - startk[b]);
    if (pos < CAP)
      bdata[(size_t)(t * NBKT + b) * CAP + pos] = u & 0x3fffff;
  }
}

// ---------------- prep: fp32->bf16 features + weight concat/pack (one dispatch) -------
// Wu[c][k]: k<128 Wl_iu; 128..255 Wr_iu+Wr_uu; 256..383 Wl_uu   (Ktot=384)
// Wi[c][k]: k<128 Wl_ui; 128..255 Wr_ui                          (Ktot=256)
struct PrepArgs {
  const float *xu, *xi;
  const float *Wl_iu[2], *Wr_iu[2], *Wr_uu[2], *Wl_uu[2], *Wl_ui[2], *Wr_ui[2];
  const float *b_iu[2], *b_uu[2], *b_ui[2];
  u16 *xb_u, *xb_i;
  u16 *Wu[2], *Wi[2];
  float *bu[2], *bi[2];
};
#define PK (128 * 384 + 128 * 256 + 256)
__global__ void prep_kernel(PrepArgs a) {
  const int n4 = NN * C / 4;
  int id = blockIdx.x * 256 + threadIdx.x;
  if (id < 2 * n4) {
    int second = id >= n4;
    int j = second ? id - n4 : id;
    float4 v = ((const float4*)(second ? a.xi : a.xu))[j];
    ushort4 o = make_ushort4(f2bf(v.x), f2bf(v.y), f2bf(v.z), f2bf(v.w));
    ((ushort4*)(second ? a.xb_i : a.xb_u))[j] = o;
    return;
  }
  int id2 = id - 2 * n4;
  if (id2 >= 2 * PK) return;
  int l = id2 / PK, j = id2 % PK;
  const int NU = 128 * 384, NI = 128 * 256;
  if (j < NU) {
    int c = j / 384, k = j % 384;
    float v = (k < 128) ? a.Wl_iu[l][c * 128 + k]
            : (k < 256) ? (a.Wr_iu[l][c * 128 + k - 128] + a.Wr_uu[l][c * 128 + k - 128])
                        : a.Wl_uu[l][c * 128 + k - 256];
    a.Wu[l][j] = f2bf(v);
  } else if (j < NU + NI) {
    int q = j - NU;
    int c = q / 256, k = q % 256;
    float v = (k < 128) ? a.Wl_ui[l][c * 128 + k] : a.Wr_ui[l][c * 128 + k - 128];
    a.Wi[l][q] = f2bf(v);
  } else {
    int q = j - NU - NI;
    if (q < 128) a.bu[l][q] = a.b_iu[l][q] + a.b_uu[l][q];
    else a.bi[l][q - 128] = a.b_ui[l][q - 128];
  }
}

// ---------------- bucket aggregation: LDS counting-sort + REGISTER accumulation ------
// One WG per bucket. Sort bucket's edges by dst-local id in LDS (64 bins), then each
// quarter-wave (16 lanes) walks 4 nodes' contiguous runs, gathering uint4 rows and
// accumulating 8 channels in registers (no LDS atomics on the hot path).
__global__ __launch_bounds__(256) void aggregate_buckets(
    u16* __restrict__ mA, u16* __restrict__ mB, u16* __restrict__ mC,
    const u16* __restrict__ xu, const u16* __restrict__ xi,
    const u32* __restrict__ bdata, const int* __restrict__ cursor) {
  __shared__ u32 stage[CAP];
  __shared__ u32 ordered[CAP];
  __shared__ int hist[64];
  __shared__ int boff[65];
  __shared__ int fillc[64];
  int tid = threadIdx.x;
  int id = blockIdx.x;                   // 0..3*NBKT-1
  int t = id / NBKT, b = id % NBKT;
  const u16* xs = (t == 1) ? xi : xu;
  u16* mean = (t == 0) ? mA : (t == 1) ? mB : mC;
  int cnt = min(cursor[id], CAP);
  if (tid < 64) hist[tid] = 0;
  __syncthreads();
  const u32* bd = bdata + (size_t)id * CAP;
  for (int i = tid; i < cnt; i += 256) {
    u32 u = bd[i];
    stage[i] = u;
    atomicAdd(&hist[(u >> 16) & 63], 1);
  }
  __syncthreads();
  if (tid < 64) {                        // wave 0: exclusive scan over 64 bins
    int v = hist[tid];
    int incl = v;
    #pragma unroll
    for (int d = 1; d < 64; d <<= 1) {
      int x = __shfl_up(incl, d, 64);
      if (tid >= d) incl += x;
    }
    boff[tid + 1] = incl;
    if (tid == 0) boff[0] = 0;
    fillc[tid] = incl - v;               // exclusive offset
  }
  __syncthreads();
  for (int i = tid; i < cnt; i += 256) {
    u32 u = stage[i];
    int slot = atomicAdd(&fillc[(u >> 16) & 63], 1);
    ordered[slot] = u;
  }
  __syncthreads();
  int qw = tid >> 4, ql = tid & 15;      // 16 quarter-waves x 16 lanes
  #pragma unroll
  for (int g = 0; g < 4; g++) {
    int dl = g * 16 + qw;
    int beg = boff[dl], end = boff[dl + 1];
    float s0 = 0.f, s1 = 0.f, s2 = 0.f, s3 = 0.f, s4 = 0.f, s5 = 0.f, s6 = 0.f, s7 = 0.f;
    int e = beg;
    for (; e + 1 < end; e += 2) {        // 2 gathers in flight per quarter-wave
      int i0 = ordered[e] & 0xffff, i1 = ordered[e + 1] & 0xffff;
      uint4 v0 = *(const uint4*)(xs + (size_t)i0 * C + ql * 8);
      uint4 v1 = *(const uint4*)(xs + (size_t)i1 * C + ql * 8);
      s0 += lo16f(v0.x) + lo16f(v1.x); s1 += hi16f(v0.x) + hi16f(v1.x);
      s2 += lo16f(v0.y) + lo16f(v1.y); s3 += hi16f(v0.y) + hi16f(v1.y);
      s4 += lo16f(v0.z) + lo16f(v1.z); s5 += hi16f(v0.z) + hi16f(v1.z);
      s6 += lo16f(v0.w) + lo16f(v1.w); s7 += hi16f(v0.w) + hi16f(v1.w);
    }
    if (e < end) {
      uint4 v0 = *(const uint4*)(xs + (size_t)(ordered[e] & 0xffff) * C + ql * 8);
      s0 += lo16f(v0.x); s1 += hi16f(v0.x);
      s2 += lo16f(v0.y); s3 += hi16f(v0.y);
      s4 += lo16f(v0.z); s5 += hi16f(v0.z);
      s6 += lo16f(v0.w); s7 += hi16f(v0.w);
    }
    int n = b * 64 + dl;
    if (n < NN) {
      float inv = 1.0f / fmaxf((float)(end - beg), 1.0f);
      uint4 o;
      o.x = (u32)f2bf(s0 * inv) | ((u32)f2bf(s1 * inv) << 16);
      o.y = (u32)f2bf(s2 * inv) | ((u32)f2bf(s3 * inv) << 16);
      o.z = (u32)f2bf(s4 * inv) | ((u32)f2bf(s5 * inv) << 16);
      o.w = (u32)f2bf(s6 * inv) | ((u32)f2bf(s7 * inv) << 16);
      *(uint4*)(mean + (size_t)n * C + ql * 8) = o;
    }
  }
}

// ---------------- fused MFMA GEMM (+bias) + LayerNorm + ReLU, both node types -------
// gridDim = (391, 2): y==0 item side (nseg=2, Ktot=256), y==1 user side (nseg=3, Ktot=384).
// BM=128 (4 waves x 32 rows), BN=128. W K-segment staged in LDS (136-u16 rows).
struct GemmArgs {
  const u16 *Ai0, *Ai1;
  const u16 *Wi; const float *bi, *lnwi, *lnbi; float* outfi; u16* outbi;
  const u16 *Au0, *Au1, *Au2;
  const u16 *Wu; const float *bu, *lnwu, *lnbu; float* outfu; u16* outbu;
};
__global__ __launch_bounds__(256) void gemm2_ln_relu(GemmArgs g) {
  __shared__ u16 Wt[128][136];
  int tid = threadIdx.x, lane = tid & 63, wv = tid >> 6;
  int arow = lane & 15, kq = (lane >> 4) * 8;
  int n0 = blockIdx.x * 128 + wv * 32;
  int user = blockIdx.y;
  const u16* As[3];
  const u16* W; const float *bias, *lnw, *lnb; float* outf; u16* outb;
  int nseg, Ktot;
  if (user) {
    As[0] = g.Au0; As[1] = g.Au1; As[2] = g.Au2; nseg = 3; Ktot = 384;
    W = g.Wu; bias = g.bu; lnw = g.lnwu; lnb = g.lnbu; outf = g.outfu; outb = g.outbu;
  } else {
    As[0] = g.Ai0; As[1] = g.Ai1; As[2] = nullptr; nseg = 2; Ktot = 256;
    W = g.Wi; bias = g.bi; lnw = g.lnwi; lnb = g.lnbi; outf = g.outfi; outb = g.outbi;
  }
  f32x4 acc[2][8];
  #pragma unroll
  for (int gg = 0; gg < 2; gg++)
    #pragma unroll
    for (int t = 0; t < 8; t++) acc[gg][t] = (f32x4){0.f, 0.f, 0.f, 0.f};

  for (int sg = 0; sg < nseg; sg++) {
    __syncthreads();
    #pragma unroll
    for (int it = 0; it < 8; it++) {            // stage 128x128 W segment (32 KB)
      int chunk = it * 256 + tid;
      int c = chunk >> 4, k8 = (chunk & 15) * 8;
      uint4 v = *(const uint4*)(W + (size_t)c * Ktot + sg * 128 + k8);
      *(uint4*)&Wt[c][k8] = v;
    }
    __syncthreads();
    const u16* Ar0 = As[sg] + (size_t)(n0 + arow) * C + kq;
    const u16* Ar1 = As[sg] + (size_t)(n0 + 16 + arow) * C + kq;
    V16 a0[4], a1[4];
    #pragma unroll
    for (int c4 = 0; c4 < 4; c4++) {
      a0[c4].u = *(const uint4*)(Ar0 + c4 * 32);
      a1[c4].u = *(const uint4*)(Ar1 + c4 * 32);
    }
    #pragma unroll
    for (int c4 = 0; c4 < 4; c4++) {
      #pragma unroll
      for (int t = 0; t < 8; t++) {
        short8 bfr = *(const short8*)&Wt[t * 16 + arow][kq + c4 * 32];
        acc[0][t] = __builtin_amdgcn_mfma_f32_16x16x32_bf16(a0[c4].s, bfr, acc[0][t], 0, 0, 0);
        acc[1][t] = __builtin_amdgcn_mfma_f32_16x16x32_bf16(a1[c4].s, bfr, acc[1][t], 0, 0, 0);
      }
    }
  }
  float bv[8], lnwv[8], lnbv[8];
  #pragma unroll
  for (int t = 0; t < 8; t++) {
    int c = t * 16 + arow;
    bv[t] = bias[c]; lnwv[t] = lnw[c]; lnbv[t] = lnb[c];
  }
  #pragma unroll
  for (int gg = 0; gg < 2; gg++) {
    #pragma unroll
    for (int r = 0; r < 4; r++) {
      float s1 = 0.f, s2 = 0.f;
      #pragma unroll
      for (int t = 0; t < 8; t++) {
        float v = acc[gg][t][r] + bv[t];
        s1 += v; s2 += v * v;
      }
      #pragma unroll
      for (int d = 1; d < 16; d <<= 1) {
        s1 += __shfl_xor(s1, d, 64);
        s2 += __shfl_xor(s2, d, 64);
      }
      float mu = s1 * (1.f / 128.f);
      float var = s2 * (1.f / 128.f) - mu * mu;
      float rs = rsqrtf(var + LN_EPS);
      int gr = n0 + gg * 16 + (lane >> 4) * 4 + r;
      if (gr < NN) {
        #pragma unroll
        for (int t = 0; t < 8; t++) {
          float y = (acc[gg][t][r] + bv[t] - mu) * rs * lnwv[t] + lnbv[t];
          y = fmaxf(y, 0.f);
          int c = t * 16 + arow;
          if (outf) outf[(size_t)gr * C + c] = y;
          else      outb[(size_t)gr * C + c] = f2bf(y);
        }
      }
    }
  }
}

extern "C" void kernel_launch(void* const* d_in, const int* in_sizes, int n_in,
                              void* d_out, int out_size, void* d_ws, size_t ws_size,
                              hipStream_t stream) {
  const float* xu = (const float*)d_in[0];
  const float* xi = (const float*)d_in[1];
  const int* ei[3] = { (const int*)d_in[2], (const int*)d_in[3], (const int*)d_in[4] };
  const float* P[26];
  for (int k = 0; k < 26; k++) P[k] = (const float*)d_in[5 + k];
  // per layer l, Q = P+13l: [0]Wl_ui [1]b_ui [2]Wr_ui [3]Wl_iu [4]b_iu [5]Wr_iu
  //                         [6]Wl_uu [7]b_uu [8]Wr_uu [9]lnw_u [10]lnb_u [11]lnw_i [12]lnb_i

  // ---- workspace (~77 MB) ----
  char* p = (char*)d_ws;
  auto alloc = [&](size_t bytes) { char* r = p; p += (bytes + 255) & ~(size_t)255; return r; };
  u32* bdata  = (u32*)alloc((size_t)3 * NBKT * CAP * 4);
  int* cursor = (int*)alloc((size_t)3 * NBKT * 4);
  u16* xb_u  = (u16*)alloc((size_t)NP * C * 2);
  u16* xb_i  = (u16*)alloc((size_t)NP * C * 2);
  u16* meanA = (u16*)alloc((size_t)NP * C * 2);
  u16* meanB = (u16*)alloc((size_t)NP * C * 2);
  u16* meanC = (u16*)alloc((size_t)NP * C * 2);
  u16 *Wu[2], *Wi[2]; float *bu[2], *bi[2];
  for (int l = 0; l < 2; l++) {
    Wu[l] = (u16*)alloc(128 * 384 * 2);
    Wi[l] = (u16*)alloc(128 * 256 * 2);
    bu[l] = (float*)alloc(128 * 4);
    bi[l] = (float*)alloc(128 * 4);
  }

  // ---- bucket binning (edges layer-invariant) ----
  hipMemsetAsync(cursor, 0, (size_t)3 * NBKT * 4, stream);
  const int nchunk = (NE + CHUNK - 1) / CHUNK;   // 74
  bin_kernel<<<3 * nchunk, 256, 0, stream>>>(bdata, cursor, ei[0], ei[1], ei[2]);

  // ---- prep: bf16 features + packed weights ----
  PrepArgs pa;
  pa.xu = xu; pa.xi = xi; pa.xb_u = xb_u; pa.xb_i = xb_i;
  for (int l = 0; l < 2; l++) {
    const float* const* Q = P + 13 * l;
    pa.Wl_iu[l] = Q[3]; pa.Wr_iu[l] = Q[5]; pa.Wr_uu[l] = Q[8]; pa.Wl_uu[l] = Q[6];
    pa.Wl_ui[l] = Q[0]; pa.Wr_ui[l] = Q[2];
    pa.b_iu[l] = Q[4]; pa.b_uu[l] = Q[7]; pa.b_ui[l] = Q[1];
    pa.Wu[l] = Wu[l]; pa.Wi[l] = Wi[l]; pa.bu[l] = bu[l]; pa.bi[l] = bi[l];
  }
  const int n4 = NN * C / 4;
  const int prep_total = 2 * n4 + 2 * PK;
  prep_kernel<<<(prep_total + 255) / 256, 256, 0, stream>>>(pa);

  for (int l = 0; l < 2; l++) {
    const float* const* Q = P + 13 * l;
    aggregate_buckets<<<3 * NBKT, 256, 0, stream>>>(meanA, meanB, meanC, xb_u, xb_i,
                                                    bdata, cursor);
    GemmArgs g;
    g.Ai0 = meanA; g.Ai1 = xb_i; g.Wi = Wi[l]; g.bi = bi[l]; g.lnwi = Q[11]; g.lnbi = Q[12];
    g.Au0 = meanB; g.Au1 = xb_u; g.Au2 = meanC; g.Wu = Wu[l]; g.bu = bu[l];
    g.lnwu = Q[9]; g.lnbu = Q[10];
    if (l == 0) {
      g.outfi = nullptr; g.outbi = xb_i;   // in place (block reads only its own rows)
      g.outfu = nullptr; g.outbu = xb_u;
    } else {
      g.outfi = (float*)d_out + (size_t)NN * C; g.outbi = nullptr;
      g.outfu = (float*)d_out;                  g.outbu = nullptr;
    }
    gemm2_ln_relu<<<dim3(NP / 128, 2), 256, 0, stream>>>(g);
  }
  (void)in_sizes; (void)n_in; (void)out_size; (void)ws_size;
}

// Round 6
// 386.255 us; speedup vs baseline: 7.1813x; 1.0434x over previous
//
#include <hip/hip_runtime.h>

#define C 128
#define NN 50000      // N_USER == N_ITEM
#define NP 50048      // padded rows: 391 * 128
#define NE 600000
#define LN_EPS 1e-5f
#define NBKT 782      // buckets per edge type: ceil(50000/64)
#define BPAD 1024
#define CHUNK 4096
#define NCHUNK ((NE + CHUNK - 1) / CHUNK)   // 147
#define CAP 1280      // bucket capacity (avg 768, +18 sigma)

typedef __attribute__((ext_vector_type(8))) short short8;
typedef __attribute__((ext_vector_type(4))) float f32x4;
typedef unsigned short u16;
typedef unsigned int u32;

union V16 { uint4 u; short8 s; };

__device__ inline float lo16f(u32 v) { union { u32 i; float f; } x; x.i = v << 16; return x.f; }
__device__ inline float hi16f(u32 v) { union { u32 i; float f; } x; x.i = v & 0xffff0000u; return x.f; }
__device__ inline u16 f2bf(float f) {
  union { float f; u32 i; } x; x.f = f;
  u32 r = (x.i + 0x7fffu + ((x.i >> 16) & 1u)) >> 16;   // RNE
  return (u16)r;
}

// ---------------- fused setup: bucket binning (blocks 0..3*NCHUNK) + prep (rest) -----
// bin: groups edges by dst bucket (dst>>6); payload u32 = (dl<<16)|src.
// prep: fp32->bf16 features + weight concat/pack.
// Wu[c][k]: k<128 Wl_iu; 128..255 Wr_iu+Wr_uu; 256..383 Wl_uu   (Ktot=384)
// Wi[c][k]: k<128 Wl_ui; 128..255 Wr_ui                          (Ktot=256)
struct SetupArgs {
  const int *e0, *e1, *e2;
  u32* bdata; int* cursor;
  const float *xu, *xi;
  const float *Wl_iu[2], *Wr_iu[2], *Wr_uu[2], *Wl_uu[2], *Wl_ui[2], *Wr_ui[2];
  const float *b_iu[2], *b_uu[2], *b_ui[2];
  u16 *xb_u, *xb_i;
  u16 *Wu[2], *Wi[2];
  float *bu[2], *bi[2];
};
#define PK (128 * 384 + 128 * 256 + 256)
#define BINB (3 * NCHUNK)

__global__ __launch_bounds__(256) void setup_kernel(SetupArgs a) {
  __shared__ u32 stage[CHUNK];     // 16 KB
  __shared__ int histk[BPAD];      // hist, then startk (overwritten in place)
  __shared__ int fillc[BPAD];
  __shared__ int gbase[BPAD];
  __shared__ int wsum[4];
  int tid = threadIdx.x;
  if (blockIdx.x < BINB) {
    int lane = tid & 63, wv = tid >> 6;
    int t = blockIdx.x / NCHUNK, ck = blockIdx.x % NCHUNK;
    const int* ei  = (t == 0) ? a.e0 : (t == 1) ? a.e1 : a.e2;
    const int* src = ei;
    const int* dst = ei + NE;
    int base = ck * CHUNK;
    int cnt = min(CHUNK, NE - base);
    for (int i = tid; i < BPAD; i += 256) histk[i] = 0;
    __syncthreads();
    for (int k = tid; k < cnt; k += 256)
      atomicAdd(&histk[dst[base + k] >> 6], 1);
    __syncthreads();
    // exclusive scan (thread owns 4 bins); histk becomes startk
    int h0 = histk[tid * 4], h1 = histk[tid * 4 + 1], h2 = histk[tid * 4 + 2], h3 = histk[tid * 4 + 3];
    int s = h0 + h1 + h2 + h3;
    int incl = s;
    #pragma unroll
    for (int d = 1; d < 64; d <<= 1) { int x = __shfl_up(incl, d, 64); if (lane >= d) incl += x; }
    if (lane == 63) wsum[wv] = incl;
    __syncthreads();
    int wbase = 0;
    for (int w = 0; w < wv; w++) wbase += wsum[w];
    int excl = wbase + incl - s;
    histk[tid * 4]     = excl;
    histk[tid * 4 + 1] = excl + h0;
    histk[tid * 4 + 2] = excl + h0 + h1;
    histk[tid * 4 + 3] = excl + h0 + h1 + h2;
    int hv[4] = { h0, h1, h2, h3 };
    #pragma unroll
    for (int j = 0; j < 4; j++) {
      int b = tid * 4 + j;
      fillc[b] = histk[b];
      gbase[b] = (hv[j] > 0 && b < NBKT) ? atomicAdd(&a.cursor[t * NBKT + b], hv[j]) : 0;
    }
    __syncthreads();
    for (int k = tid; k < cnt; k += 256) {
      int d = dst[base + k], sv = src[base + k];
      int b = d >> 6;
      int slot = atomicAdd(&fillc[b], 1);
      stage[slot] = ((u32)b << 22) | ((u32)(d & 63) << 16) | (u32)sv;
    }
    __syncthreads();
    for (int i = tid; i < cnt; i += 256) {
      u32 u = stage[i];
      int b = u >> 22;
      int pos = gbase[b] + (i - histk[b]);
      if (pos < CAP)
        a.bdata[(size_t)(t * NBKT + b) * CAP + pos] = u & 0x3fffff;
    }
    return;
  }
  // ---- prep part ----
  const int n4 = NN * C / 4;
  int id = (blockIdx.x - BINB) * 256 + tid;
  if (id < 2 * n4) {
    int second = id >= n4;
    int j = second ? id - n4 : id;
    float4 v = ((const float4*)(second ? a.xi : a.xu))[j];
    ushort4 o = make_ushort4(f2bf(v.x), f2bf(v.y), f2bf(v.z), f2bf(v.w));
    ((ushort4*)(second ? a.xb_i : a.xb_u))[j] = o;
    return;
  }
  int id2 = id - 2 * n4;
  if (id2 >= 2 * PK) return;
  int l = id2 / PK, j = id2 % PK;
  const int NU = 128 * 384, NI = 128 * 256;
  if (j < NU) {
    int c = j / 384, k = j % 384;
    float v = (k < 128) ? a.Wl_iu[l][c * 128 + k]
            : (k < 256) ? (a.Wr_iu[l][c * 128 + k - 128] + a.Wr_uu[l][c * 128 + k - 128])
                        : a.Wl_uu[l][c * 128 + k - 256];
    a.Wu[l][j] = f2bf(v);
  } else if (j < NU + NI) {
    int q = j - NU;
    int c = q / 256, k = q % 256;
    float v = (k < 128) ? a.Wl_ui[l][c * 128 + k] : a.Wr_ui[l][c * 128 + k - 128];
    a.Wi[l][q] = f2bf(v);
  } else {
    int q = j - NU - NI;
    if (q < 128) a.bu[l][q] = a.b_iu[l][q] + a.b_uu[l][q];
    else a.bi[l][q - 128] = a.b_ui[l][q - 128];
  }
}

// ---------------- bucket aggregation: LDS counting-sort + register accumulation ------
// One WG per bucket. Sort edges by dst-local id in LDS, then each quarter-wave walks
// 4 nodes' contiguous runs, gathering uint4 rows, accumulating in registers (unroll 4).
__global__ __launch_bounds__(256) void aggregate_buckets(
    u16* __restrict__ mA, u16* __restrict__ mB, u16* __restrict__ mC,
    const u16* __restrict__ xu, const u16* __restrict__ xi,
    const u32* __restrict__ bdata, const int* __restrict__ cursor) {
  __shared__ u32 stage[CAP];
  __shared__ u32 ordered[CAP];
  __shared__ int hist[64];
  __shared__ int boff[65];
  __shared__ int fillc[64];
  int tid = threadIdx.x;
  int id = blockIdx.x;                   // 0..3*NBKT-1
  int t = id / NBKT, b = id % NBKT;
  const u16* xs = (t == 1) ? xi : xu;
  u16* mean = (t == 0) ? mA : (t == 1) ? mB : mC;
  int cnt = min(cursor[id], CAP);
  if (tid < 64) hist[tid] = 0;
  __syncthreads();
  const u32* bd = bdata + (size_t)id * CAP;
  for (int i = tid; i < cnt; i += 256) {
    u32 u = bd[i];
    stage[i] = u;
    atomicAdd(&hist[(u >> 16) & 63], 1);
  }
  __syncthreads();
  if (tid < 64) {                        // wave 0: exclusive scan over 64 bins
    int v = hist[tid];
    int incl = v;
    #pragma unroll
    for (int d = 1; d < 64; d <<= 1) {
      int x = __shfl_up(incl, d, 64);
      if (tid >= d) incl += x;
    }
    boff[tid + 1] = incl;
    if (tid == 0) boff[0] = 0;
    fillc[tid] = incl - v;
  }
  __syncthreads();
  for (int i = tid; i < cnt; i += 256) {
    u32 u = stage[i];
    int slot = atomicAdd(&fillc[(u >> 16) & 63], 1);
    ordered[slot] = u;
  }
  __syncthreads();
  int qw = tid >> 4, ql = tid & 15;      // 16 quarter-waves x 16 lanes
  #pragma unroll
  for (int g = 0; g < 4; g++) {
    int dl = g * 16 + qw;
    int beg = boff[dl], end = boff[dl + 1];
    float s0 = 0.f, s1 = 0.f, s2 = 0.f, s3 = 0.f, s4 = 0.f, s5 = 0.f, s6 = 0.f, s7 = 0.f;
    int e = beg;
    for (; e + 3 < end; e += 4) {        // 4 gathers in flight per quarter-wave
      uint4 v0 = *(const uint4*)(xs + (size_t)(ordered[e]     & 0xffff) * C + ql * 8);
      uint4 v1 = *(const uint4*)(xs + (size_t)(ordered[e + 1] & 0xffff) * C + ql * 8);
      uint4 v2 = *(const uint4*)(xs + (size_t)(ordered[e + 2] & 0xffff) * C + ql * 8);
      uint4 v3 = *(const uint4*)(xs + (size_t)(ordered[e + 3] & 0xffff) * C + ql * 8);
      s0 += (lo16f(v0.x) + lo16f(v1.x)) + (lo16f(v2.x) + lo16f(v3.x));
      s1 += (hi16f(v0.x) + hi16f(v1.x)) + (hi16f(v2.x) + hi16f(v3.x));
      s2 += (lo16f(v0.y) + lo16f(v1.y)) + (lo16f(v2.y) + lo16f(v3.y));
      s3 += (hi16f(v0.y) + hi16f(v1.y)) + (hi16f(v2.y) + hi16f(v3.y));
      s4 += (lo16f(v0.z) + lo16f(v1.z)) + (lo16f(v2.z) + lo16f(v3.z));
      s5 += (hi16f(v0.z) + hi16f(v1.z)) + (hi16f(v2.z) + hi16f(v3.z));
      s6 += (lo16f(v0.w) + lo16f(v1.w)) + (lo16f(v2.w) + lo16f(v3.w));
      s7 += (hi16f(v0.w) + hi16f(v1.w)) + (hi16f(v2.w) + hi16f(v3.w));
    }
    for (; e < end; e++) {
      uint4 v0 = *(const uint4*)(xs + (size_t)(ordered[e] & 0xffff) * C + ql * 8);
      s0 += lo16f(v0.x); s1 += hi16f(v0.x);
      s2 += lo16f(v0.y); s3 += hi16f(v0.y);
      s4 += lo16f(v0.z); s5 += hi16f(v0.z);
      s6 += lo16f(v0.w); s7 += hi16f(v0.w);
    }
    int n = b * 64 + dl;
    if (n < NN) {
      float inv = 1.0f / fmaxf((float)(end - beg), 1.0f);
      uint4 o;
      o.x = (u32)f2bf(s0 * inv) | ((u32)f2bf(s1 * inv) << 16);
      o.y = (u32)f2bf(s2 * inv) | ((u32)f2bf(s3 * inv) << 16);
      o.z = (u32)f2bf(s4 * inv) | ((u32)f2bf(s5 * inv) << 16);
      o.w = (u32)f2bf(s6 * inv) | ((u32)f2bf(s7 * inv) << 16);
      *(uint4*)(mean + (size_t)n * C + ql * 8) = o;
    }
  }
}

// ---------------- fused MFMA GEMM (+bias) + LayerNorm + ReLU, both node types -------
// gridDim = (391, 2): y==0 item side (nseg=2, Ktot=256), y==1 user side (nseg=3, Ktot=384).
// BM=128 (4 waves x 32 rows), BN=128. W K-segment staged in LDS (136-u16 rows).
struct GemmArgs {
  const u16 *Ai0, *Ai1;
  const u16 *Wi; const float *bi, *lnwi, *lnbi; float* outfi; u16* outbi;
  const u16 *Au0, *Au1, *Au2;
  const u16 *Wu; const float *bu, *lnwu, *lnbu; float* outfu; u16* outbu;
};
__global__ __launch_bounds__(256) void gemm2_ln_relu(GemmArgs g) {
  __shared__ u16 Wt[128][136];
  int tid = threadIdx.x, lane = tid & 63, wv = tid >> 6;
  int arow = lane & 15, kq = (lane >> 4) * 8;
  int n0 = blockIdx.x * 128 + wv * 32;
  int user = blockIdx.y;
  const u16* As[3];
  const u16* W; const float *bias, *lnw, *lnb; float* outf; u16* outb;
  int nseg, Ktot;
  if (user) {
    As[0] = g.Au0; As[1] = g.Au1; As[2] = g.Au2; nseg = 3; Ktot = 384;
    W = g.Wu; bias = g.bu; lnw = g.lnwu; lnb = g.lnbu; outf = g.outfu; outb = g.outbu;
  } else {
    As[0] = g.Ai0; As[1] = g.Ai1; As[2] = nullptr; nseg = 2; Ktot = 256;
    W = g.Wi; bias = g.bi; lnw = g.lnwi; lnb = g.lnbi; outf = g.outfi; outb = g.outbi;
  }
  f32x4 acc[2][8];
  #pragma unroll
  for (int gg = 0; gg < 2; gg++)
    #pragma unroll
    for (int t = 0; t < 8; t++) acc[gg][t] = (f32x4){0.f, 0.f, 0.f, 0.f};

  for (int sg = 0; sg < nseg; sg++) {
    __syncthreads();
    #pragma unroll
    for (int it = 0; it < 8; it++) {            // stage 128x128 W segment (32 KB)
      int chunk = it * 256 + tid;
      int c = chunk >> 4, k8 = (chunk & 15) * 8;
      uint4 v = *(const uint4*)(W + (size_t)c * Ktot + sg * 128 + k8);
      *(uint4*)&Wt[c][k8] = v;
    }
    __syncthreads();
    const u16* Ar0 = As[sg] + (size_t)(n0 + arow) * C + kq;
    const u16* Ar1 = As[sg] + (size_t)(n0 + 16 + arow) * C + kq;
    V16 a0[4], a1[4];
    #pragma unroll
    for (int c4 = 0; c4 < 4; c4++) {
      a0[c4].u = *(const uint4*)(Ar0 + c4 * 32);
      a1[c4].u = *(const uint4*)(Ar1 + c4 * 32);
    }
    #pragma unroll
    for (int c4 = 0; c4 < 4; c4++) {
      #pragma unroll
      for (int t = 0; t < 8; t++) {
        short8 bfr = *(const short8*)&Wt[t * 16 + arow][kq + c4 * 32];
        acc[0][t] = __builtin_amdgcn_mfma_f32_16x16x32_bf16(a0[c4].s, bfr, acc[0][t], 0, 0, 0);
        acc[1][t] = __builtin_amdgcn_mfma_f32_16x16x32_bf16(a1[c4].s, bfr, acc[1][t], 0, 0, 0);
      }
    }
  }
  float bv[8], lnwv[8], lnbv[8];
  #pragma unroll
  for (int t = 0; t < 8; t++) {
    int c = t * 16 + arow;
    bv[t] = bias[c]; lnwv[t] = lnw[c]; lnbv[t] = lnb[c];
  }
  #pragma unroll
  for (int gg = 0; gg < 2; gg++) {
    #pragma unroll
    for (int r = 0; r < 4; r++) {
      float s1 = 0.f, s2 = 0.f;
      #pragma unroll
      for (int t = 0; t < 8; t++) {
        float v = acc[gg][t][r] + bv[t];
        s1 += v; s2 += v * v;
      }
      #pragma unroll
      for (int d = 1; d < 16; d <<= 1) {
        s1 += __shfl_xor(s1, d, 64);
        s2 += __shfl_xor(s2, d, 64);
      }
      float mu = s1 * (1.f / 128.f);
      float var = s2 * (1.f / 128.f) - mu * mu;
      float rs = rsqrtf(var + LN_EPS);
      int gr = n0 + gg * 16 + (lane >> 4) * 4 + r;
      if (gr < NN) {
        #pragma unroll
        for (int t = 0; t < 8; t++) {
          float y = (acc[gg][t][r] + bv[t] - mu) * rs * lnwv[t] + lnbv[t];
          y = fmaxf(y, 0.f);
          int c = t * 16 + arow;
          if (outf) outf[(size_t)gr * C + c] = y;
          else      outb[(size_t)gr * C + c] = f2bf(y);
        }
      }
    }
  }
}

extern "C" void kernel_launch(void* const* d_in, const int* in_sizes, int n_in,
                              void* d_out, int out_size, void* d_ws, size_t ws_size,
                              hipStream_t stream) {
  const float* xu = (const float*)d_in[0];
  const float* xi = (const float*)d_in[1];
  const int* ei[3] = { (const int*)d_in[2], (const int*)d_in[3], (const int*)d_in[4] };
  const float* P[26];
  for (int k = 0; k < 26; k++) P[k] = (const float*)d_in[5 + k];
  // per layer l, Q = P+13l: [0]Wl_ui [1]b_ui [2]Wr_ui [3]Wl_iu [4]b_iu [5]Wr_iu
  //                         [6]Wl_uu [7]b_uu [8]Wr_uu [9]lnw_u [10]lnb_u [11]lnw_i [12]lnb_i

  // ---- workspace (~77 MB) ----
  char* p = (char*)d_ws;
  auto alloc = [&](size_t bytes) { char* r = p; p += (bytes + 255) & ~(size_t)255; return r; };
  u32* bdata  = (u32*)alloc((size_t)3 * NBKT * CAP * 4);
  int* cursor = (int*)alloc((size_t)3 * NBKT * 4);
  u16* xb_u  = (u16*)alloc((size_t)NP * C * 2);
  u16* xb_i  = (u16*)alloc((size_t)NP * C * 2);
  u16* meanA = (u16*)alloc((size_t)NP * C * 2);
  u16* meanB = (u16*)alloc((size_t)NP * C * 2);
  u16* meanC = (u16*)alloc((size_t)NP * C * 2);
  u16 *Wu[2], *Wi[2]; float *bu[2], *bi[2];
  for (int l = 0; l < 2; l++) {
    Wu[l] = (u16*)alloc(128 * 384 * 2);
    Wi[l] = (u16*)alloc(128 * 256 * 2);
    bu[l] = (float*)alloc(128 * 4);
    bi[l] = (float*)alloc(128 * 4);
  }

  // ---- fused setup: binning + bf16 converts + weight packs ----
  hipMemsetAsync(cursor, 0, (size_t)3 * NBKT * 4, stream);
  SetupArgs sa;
  sa.e0 = ei[0]; sa.e1 = ei[1]; sa.e2 = ei[2];
  sa.bdata = bdata; sa.cursor = cursor;
  sa.xu = xu; sa.xi = xi; sa.xb_u = xb_u; sa.xb_i = xb_i;
  for (int l = 0; l < 2; l++) {
    const float* const* Q = P + 13 * l;
    sa.Wl_iu[l] = Q[3]; sa.Wr_iu[l] = Q[5]; sa.Wr_uu[l] = Q[8]; sa.Wl_uu[l] = Q[6];
    sa.Wl_ui[l] = Q[0]; sa.Wr_ui[l] = Q[2];
    sa.b_iu[l] = Q[4]; sa.b_uu[l] = Q[7]; sa.b_ui[l] = Q[1];
    sa.Wu[l] = Wu[l]; sa.Wi[l] = Wi[l]; sa.bu[l] = bu[l]; sa.bi[l] = bi[l];
  }
  const int n4 = NN * C / 4;
  const int prep_blocks = (2 * n4 + 2 * PK + 255) / 256;
  setup_kernel<<<BINB + prep_blocks, 256, 0, stream>>>(sa);

  for (int l = 0; l < 2; l++) {
    const float* const* Q = P + 13 * l;
    aggregate_buckets<<<3 * NBKT, 256, 0, stream>>>(meanA, meanB, meanC, xb_u, xb_i,
                                                    bdata, cursor);
    GemmArgs g;
    g.Ai0 = meanA; g.Ai1 = xb_i; g.Wi = Wi[l]; g.bi = bi[l]; g.lnwi = Q[11]; g.lnbi = Q[12];
    g.Au0 = meanB; g.Au1 = xb_u; g.Au2 = meanC; g.Wu = Wu[l]; g.bu = bu[l];
    g.lnwu = Q[9]; g.lnbu = Q[10];
    if (l == 0) {
      g.outfi = nullptr; g.outbi = xb_i;   // in place (block reads only its own rows)
      g.outfu = nullptr; g.outbu = xb_u;
    } else {
      g.outfi = (float*)d_out + (size_t)NN * C; g.outbi = nullptr;
      g.outfu = (float*)d_out;                  g.outbu = nullptr;
    }
    gemm2_ln_relu<<<dim3(NP / 128, 2), 256, 0, stream>>>(g);
  }
  (void)in_sizes; (void)n_in; (void)out_size; (void)ws_size;
}